// Round 26
// baseline (56.056 us; speedup 1.0000x reference)
//
#include <hip/hip_runtime.h>
#include <math.h>

typedef _Float16 f16;
typedef _Float16 f16x2 __attribute__((ext_vector_type(2)));
typedef _Float16 f16x4 __attribute__((ext_vector_type(4)));
typedef _Float16 f16x8 __attribute__((ext_vector_type(8)));
typedef float f32x4 __attribute__((ext_vector_type(4)));

#if defined(__has_builtin)
#if __has_builtin(__builtin_amdgcn_fdot2)
#define USE_FDOT2 1
#endif
#if __has_builtin(__builtin_amdgcn_exp2f)
#define USE_EXP2 1
#endif
#if __has_builtin(__builtin_amdgcn_cvt_pkrtz)
#define USE_PKRTZ 1
#endif
#endif

__device__ __forceinline__ float fdot2f(f16x2 a, f16x2 b, float c) {
#ifdef USE_FDOT2
    return __builtin_amdgcn_fdot2(a, b, c, false);
#else
    return c + (float)a.x * (float)b.x + (float)a.y * (float)b.y;
#endif
}
__device__ __forceinline__ float exp2fast(float a) {
#ifdef USE_EXP2
    return __builtin_amdgcn_exp2f(a);
#else
    return exp2f(a);
#endif
}
__device__ __forceinline__ f16x2 pk2(float a, float b) {
#ifdef USE_PKRTZ
    auto r0 = __builtin_amdgcn_cvt_pkrtz(a, b);
    f16x2 r; __builtin_memcpy(&r, &r0, 4); return r;
#else
    return (f16x2){(f16)a, (f16)b};
#endif
}
__device__ __forceinline__ int f16x2_as_int(f16x2 v) { int r; __builtin_memcpy(&r, &v, 4); return r; }
__device__ __forceinline__ f16x2 int_as_f16x2(int v) { f16x2 r; __builtin_memcpy(&r, &v, 4); return r; }

namespace {
// ---- k_att constants (ql-free: 28160B LDS -> 5 blocks/CU) ----
constexpr int KS  = 40;
constexpr int VTS = 200;
constexpr int OFF_KL = 0;            // 192*40*2 = 15360
constexpr int OFF_VT = 15360;        // 12800 -> 28160
constexpr int ATT_LDS = 28160;       // x5 = 140800 <= 160K -> 5 blocks/CU
constexpr float C1  = 0.2550600f;
constexpr float CZN = -5.7707801f;
constexpr float CZV = 2.5511480f;

// ---- weights in MFMA B-FRAGMENT layout [ot][ks][lg][lr][j] f16 ----
constexpr int FR_WQ  = 0;        // IN=64  OUT=128 -> 8192
constexpr int FR_WKV = 8192;     // IN=64  OUT=256 -> 16384
constexpr int FR_WO  = 24576;    // IN=128 OUT=64  -> 8192
constexpr int FR_W1  = 32768;    // IN=64  OUT=128 -> 8192
constexpr int FR_W2  = 40960;    // IN=128 OUT=64  -> 8192
constexpr int NWF    = 49152;    // total f16 (96 KB)
constexpr int CONV_BLOCKS = NWF / 256;   // 192

// ---- k_epi constants (r26: f16 tv -> 37888B LDS -> 4 blocks/CU) ----
constexpr int EOLS = 136;
constexpr int ETVS = 72;    // f16/row tv now
constexpr int EH2S = 72;
constexpr int OFF_EOL = 0;                   // 64*136*2 = 17408
constexpr int OFF_ETV = 17408;               // 64*72*2  = 9216 -> 26624
constexpr int OFF_EH2 = 26624;               // 64*72*2  = 9216 -> 35840
constexpr int OFF_ERD = 35840;               // 64*4*2 f32 = 2048 -> 37888
constexpr int EPI_LDS = 37888;               // x4 = 151552 <= 160K -> 4 blocks/CU
}

__device__ f16 g_wfrag[NWF];
// g_h in MFMA A-FRAGMENT layout: [tokblk(4096)][ks(2)][lg(4)][lr(16)][j(8)] f16.
__device__ f16 g_h[65536 * 64];

__device__ __forceinline__ const f16x8* hfrag(size_t tokblk, int ks, int lg, int lr) {
    return (const f16x8*)(g_h + (((tokblk * 2 + ks) * 4 + lg) * 16 + lr) * 8);
}
__device__ __forceinline__ const f16x8* wfrag(int base, int nks, int ot, int ks, int lg, int lr) {
    return (const f16x8*)(g_wfrag + base + (((ot * nks + ks) * 4 + lg) * 16 + lr) * 8);
}

// ---------------- Kernel 0 (merged): weight repack + LN1 -> g_h ----------------
__global__ __launch_bounds__(256, 8) void k_convln(
    const float* __restrict__ Wq, const float* __restrict__ Wkv,
    const float* __restrict__ Wo, const float* __restrict__ W1,
    const float* __restrict__ W2,
    const float* __restrict__ x,
    const float* __restrict__ ln1_s, const float* __restrict__ ln1_b) {
    const int bid = blockIdx.x;
    if (bid < CONV_BLOCKS) {
        const int i = bid * 256 + threadIdx.x;      // f16 element index
        const float* src; int IN, OUT, base;
        if (i < FR_WKV)      { src = Wq;  IN = 64;  OUT = 128; base = FR_WQ;  }
        else if (i < FR_WO)  { src = Wkv; IN = 64;  OUT = 256; base = FR_WKV; }
        else if (i < FR_W1)  { src = Wo;  IN = 128; OUT = 64;  base = FR_WO;  }
        else if (i < FR_W2)  { src = W1;  IN = 64;  OUT = 128; base = FR_W1;  }
        else                 { src = W2;  IN = 128; OUT = 64;  base = FR_W2;  }
        const int local = i - base;
        const int j  = local & 7;
        const int lr = (local >> 3) & 15;
        const int lg = (local >> 7) & 3;
        const int nks = IN >> 5;
        const int ks = (local >> 9) & (nks - 1);
        const int ot = local >> (9 + ((nks == 2) ? 1 : 2));
        const int in  = ks * 32 + lg * 8 + j;
        const int out = ot * 16 + lr;
        g_wfrag[i] = (f16)src[in * OUT + out];
        return;
    }
    // LN1 part: 1024 blocks of 64 tokens, 4 threads/token
    const int lb = bid - CONV_BLOCKS;
    const int tid = threadIdx.x;
    const size_t tok = (size_t)lb * 64 + (tid >> 2);
    const int q = tid & 3;
    const float* xr = x + tok * 64 + q * 16;
    float v[16];
    {
        const float4 a = ((const float4*)xr)[0], b = ((const float4*)xr)[1];
        const float4 c = ((const float4*)xr)[2], d = ((const float4*)xr)[3];
        v[0]=a.x; v[1]=a.y; v[2]=a.z; v[3]=a.w;  v[4]=b.x; v[5]=b.y; v[6]=b.z; v[7]=b.w;
        v[8]=c.x; v[9]=c.y; v[10]=c.z; v[11]=c.w; v[12]=d.x; v[13]=d.y; v[14]=d.z; v[15]=d.w;
    }
    float s = 0.f, ss = 0.f;
    #pragma unroll
    for (int j = 0; j < 16; ++j) { s += v[j]; ss += v[j]*v[j]; }
    s  += __shfl_xor(s, 1);  s  += __shfl_xor(s, 2);
    ss += __shfl_xor(ss, 1); ss += __shfl_xor(ss, 2);
    const float mean = s * 0.015625f;
    const float rstd = rsqrtf(ss * 0.015625f - mean*mean + 1e-5f);
    f16x8 p0, p1;
    #pragma unroll
    for (int j = 0; j < 8; ++j) {
        p0[j] = (f16)((v[j]     - mean) * rstd * ln1_s[q*16 + j]     + ln1_b[q*16 + j]);
        p1[j] = (f16)((v[j + 8] - mean) * rstd * ln1_s[q*16 + j + 8] + ln1_b[q*16 + j + 8]);
    }
    const size_t tokblk = tok >> 4;
    const int lr = (int)(tok & 15);
    const int ks = q >> 1, lg0 = (q & 1) * 2;
    *(f16x8*)(g_h + (((tokblk * 2 + ks) * 4 + lg0) * 16 + lr) * 8)     = p0;
    *(f16x8*)(g_h + (((tokblk * 2 + ks) * 4 + lg0 + 1) * 16 + lr) * 8) = p1;
}

// ---------------- Kernel 1: per-(window,head) attention; P AND Q in registers ----------
__global__ __launch_bounds__(256, 5) void k_att(
    const float* __restrict__ bkv,
    f16* __restrict__ o_out)
{
    __shared__ __align__(16) char smem[ATT_LDS];
    f16* kl   = (f16*)(smem + OFF_KL);
    f16* vt   = (f16*)(smem + OFF_VT);

    const int tid  = threadIdx.x;
    const int bid  = blockIdx.x;
    const int w    = bid & 511;
    const int head = bid >> 9;
    const int cb   = head * 32;
    const int n    = w & 255;
    const int t    = w >> 8;

    const int lane = tid & 63, wv = tid >> 6;
    const int lr = lane & 15, lg = lane >> 4;
    const int mA = wv * 32;

    // Phase C: K/V projections -> LDS; Q projection -> registers (B-frag via shuffle)
    f16x8 bq0, bq1;
    {
        #pragma unroll
        for (int mi = 0; mi < 3; ++mi) {
            const int seg = wv * 3 + mi;                    // 0..11
            const int v_ = seg / 6;
            const int t2 = (seg % 6) + ((t == 0) ? 2 : 0);
            int tsrc, tt;
            if (t2 < 2)      { tsrc = t - 1; tt = t2 + 2; }
            else if (t2 < 6) { tsrc = t;     tt = t2 - 2; }
            else             { tsrc = t + 1; tt = t2 - 6; }
            const size_t tokblk = (size_t)(v_ * 8 + tsrc * 4 + tt) * 256 + n;
            const int mb = seg * 16;
            #pragma unroll
            for (int nt = 0; nt < 2; ++nt) {
                f32x4 ck = {0.f,0.f,0.f,0.f}, cv = {0.f,0.f,0.f,0.f};
                #pragma unroll
                for (int ks = 0; ks < 2; ++ks) {
                    const f16x8 af = *hfrag(tokblk, ks, lg, lr);
                    const f16x8 bk = *wfrag(FR_WKV, 2, head*2 + nt, ks, lg, lr);
                    const f16x8 bv = *wfrag(FR_WKV, 2, 8 + head*2 + nt, ks, lg, lr);
                    ck = __builtin_amdgcn_mfma_f32_16x16x32_f16(af, bk, ck, 0, 0, 0);
                    cv = __builtin_amdgcn_mfma_f32_16x16x32_f16(af, bv, cv, 0, 0, 0);
                }
                const float bk_b = bkv[cb + nt*16 + lr];
                const float bv_b = bkv[128 + cb + nt*16 + lr];
                #pragma unroll
                for (int e = 0; e < 4; ++e) {
                    const int row = mb + lg*4 + e;
                    kl[row * KS + nt*16 + lr] = (f16)(ck[e] + bk_b);
                    vt[(nt*16 + lr) * VTS + row] = (f16)(cv[e] + bv_b);
                }
            }
        }
        // Q: wave-local shuffle transpose from C-layout to B-frag
        #pragma unroll
        for (int mi = 0; mi < 2; ++mi) {
            const int qm = wv * 2 + mi;
            const int v_ = qm >> 2, tt = qm & 3;
            const size_t tokblk = (size_t)(v_ * 8 + t * 4 + tt) * 256 + n;
            int pkA[2], pkB[2];
            #pragma unroll
            for (int nt = 0; nt < 2; ++nt) {
                f32x4 cq = {0.f,0.f,0.f,0.f};
                #pragma unroll
                for (int ks = 0; ks < 2; ++ks) {
                    const f16x8 af = *hfrag(tokblk, ks, lg, lr);
                    const f16x8 bq = *wfrag(FR_WQ, 2, head*2 + nt, ks, lg, lr);
                    cq = __builtin_amdgcn_mfma_f32_16x16x32_f16(af, bq, cq, 0, 0, 0);
                }
                pkA[nt] = f16x2_as_int(pk2(cq[0], cq[1]));
                pkB[nt] = f16x2_as_int(pk2(cq[2], cq[3]));
            }
            f16x8 bq_;
            #pragma unroll
            for (int j = 0; j < 8; ++j) {
                const int sl = (lr >> 2) * 16 + (lg & 1) * 8 + j;
                const int a0 = __shfl(pkA[0], sl), b0 = __shfl(pkB[0], sl);
                const int a1 = __shfl(pkA[1], sl), b1 = __shfl(pkB[1], sl);
                const int s0 = (lr & 2) ? b0 : a0;
                const int s1 = (lr & 2) ? b1 : a1;
                const f16x2 vv = int_as_f16x2((lg >= 2) ? s1 : s0);
                bq_[j] = (lr & 1) ? vv.y : vv.x;
            }
            if (mi == 0) bq0 = bq_; else bq1 = bq_;
        }
    }

    // pz from register q (B-frag layout)
    float pz0, pz1;
    {
        float s0 = 0.f, s1 = 0.f;
        #pragma unroll
        for (int j = 0; j < 8; ++j) {
            const float wgt = bkv[cb + lg*8 + j];
            s0 += (float)bq0[j] * wgt;
            s1 += (float)bq1[j] * wgt;
        }
        s0 += __shfl_xor(s0, 16); s0 += __shfl_xor(s0, 32);
        s1 += __shfl_xor(s1, 16); s1 += __shfl_xor(s1, 32);
        pz0 = exp2fast(fmaf(s0, C1, CZV));
        pz1 = exp2fast(fmaf(s1, C1, CZV));
    }

    __syncthreads();   // kl/vt ready (the kernel's only barrier)

    f32x4 oc00 = {0.f,0.f,0.f,0.f}, oc01 = {0.f,0.f,0.f,0.f};
    f32x4 oc10 = {0.f,0.f,0.f,0.f}, oc11 = {0.f,0.f,0.f,0.f};
    float l0 = 0.f, l1 = 0.f;

    #pragma unroll 1
    for (int kk = 0; kk < 6; ++kk) {
        const f16x8 ak0 = *(const f16x8*)(kl + (kk*32 + lr) * KS + lg * 8);
        const f16x8 ak1 = *(const f16x8*)(kl + (kk*32 + 16 + lr) * KS + lg * 8);
        const f32x4 ct00 = __builtin_amdgcn_mfma_f32_16x16x32_f16(ak0, bq0, (f32x4){0.f,0.f,0.f,0.f}, 0, 0, 0);
        const f32x4 ct01 = __builtin_amdgcn_mfma_f32_16x16x32_f16(ak0, bq1, (f32x4){0.f,0.f,0.f,0.f}, 0, 0, 0);
        const f32x4 ct10 = __builtin_amdgcn_mfma_f32_16x16x32_f16(ak1, bq0, (f32x4){0.f,0.f,0.f,0.f}, 0, 0, 0);
        const f32x4 ct11 = __builtin_amdgcn_mfma_f32_16x16x32_f16(ak1, bq1, (f32x4){0.f,0.f,0.f,0.f}, 0, 0, 0);

        float p00[4], p01[4], p10[4], p11[4];
        #pragma unroll
        for (int e = 0; e < 4; ++e) {
            p00[e] = exp2fast(fmaf(ct00[e], C1, CZN));
            p01[e] = exp2fast(fmaf(ct01[e], C1, CZN));
            p10[e] = exp2fast(fmaf(ct10[e], C1, CZN));
            p11[e] = exp2fast(fmaf(ct11[e], C1, CZN));
        }
        #pragma unroll
        for (int e = 0; e < 4; ++e) { l0 += p00[e] + p10[e]; l1 += p01[e] + p11[e]; }

        int pk0[4], pk1[4];
        #pragma unroll
        for (int e = 0; e < 4; ++e) {
            pk0[e] = f16x2_as_int(pk2(p00[e], p10[e]));
            pk1[e] = f16x2_as_int(pk2(p01[e], p11[e]));
        }
        f16x8 bp0, bp1;
        #pragma unroll
        for (int j = 0; j < 8; ++j) {
            const int sl = ((lg & 1) * 2 + (j >> 2)) * 16 + lr;
            const f16x2 v0 = int_as_f16x2(__shfl(pk0[j & 3], sl));
            const f16x2 v1 = int_as_f16x2(__shfl(pk1[j & 3], sl));
            bp0[j] = (lg < 2) ? v0.x : v0.y;
            bp1[j] = (lg < 2) ? v1.x : v1.y;
        }

        const f16x8 av0 = *(const f16x8*)(vt + lr * VTS + kk*32 + lg*8);
        const f16x8 av1 = *(const f16x8*)(vt + (16 + lr) * VTS + kk*32 + lg*8);
        oc00 = __builtin_amdgcn_mfma_f32_16x16x32_f16(av0, bp0, oc00, 0, 0, 0);
        oc01 = __builtin_amdgcn_mfma_f32_16x16x32_f16(av0, bp1, oc01, 0, 0, 0);
        oc10 = __builtin_amdgcn_mfma_f32_16x16x32_f16(av1, bp0, oc10, 0, 0, 0);
        oc11 = __builtin_amdgcn_mfma_f32_16x16x32_f16(av1, bp1, oc11, 0, 0, 0);
    }

    l0 += __shfl_xor(l0, 16); l0 += __shfl_xor(l0, 32);
    l1 += __shfl_xor(l1, 16); l1 += __shfl_xor(l1, 32);

    const float inv0 = 1.0f / (l0 + pz0), pzn0 = pz0 * inv0;
    const float inv1 = 1.0f / (l1 + pz1), pzn1 = pz1 * inv1;

    // epilogue: one f16x4 store per tile (r26: was 4x 2B stores)
    #define EPI_TILE(CC, MT, QT, INVQ, PZQ) { \
        const int q = mA + (QT) * 16 + lr; \
        const int v2 = q >> 6, tt2 = (q >> 4) & 3, nn2 = (q >> 2) & 3, dd2 = q & 3; \
        const size_t tk = ((size_t)(v2 * 8 + t * 4 + tt2) * 1024 + n * 4 + nn2) * 4 + dd2; \
        float oo[4]; \
        _Pragma("unroll") \
        for (int e = 0; e < 4; ++e) { \
            const int ch = (MT) * 16 + lg * 4 + e; \
            oo[e] = fmaf(PZQ, bkv[128 + cb + ch], CC[e] * (INVQ)); \
        } \
        const f16x2 lo_ = pk2(oo[0], oo[1]), hi_ = pk2(oo[2], oo[3]); \
        const f16x4 st_ = {lo_.x, lo_.y, hi_.x, hi_.y}; \
        *(f16x4*)(o_out + tk * 128 + cb + (MT) * 16 + lg * 4) = st_; \
    }
    EPI_TILE(oc00, 0, 0, inv0, pzn0)
    EPI_TILE(oc01, 0, 1, inv1, pzn1)
    EPI_TILE(oc10, 1, 0, inv0, pzn0)
    EPI_TILE(oc11, 1, 1, inv1, pzn1)
    #undef EPI_TILE
}

// ---------------- Kernel 2: MFMA epilogue, 64 tokens/block ----------------
// r26: tv stored as f16 (stats still f32) -> LDS 37888 -> 4 blocks/CU.
__global__ __launch_bounds__(256, 4) void k_epi(
    const float* __restrict__ x, const f16* __restrict__ o_in,
    const float* __restrict__ bo, const float* __restrict__ gamma,
    const float* __restrict__ ln2_s, const float* __restrict__ ln2_b,
    const float* __restrict__ b1, const float* __restrict__ b2,
    const float* __restrict__ gm, float* __restrict__ out)
{
    __shared__ __align__(16) char smem[EPI_LDS];
    f16* eol    = (f16*)(smem + OFF_EOL);    // [64][136] o rows; hid overlays
    f16* etv    = (f16*)(smem + OFF_ETV);    // [64][72] tv (f16)
    f16* eh2    = (f16*)(smem + OFF_EH2);    // [64][72] LN2 output
    float* erd  = (float*)(smem + OFF_ERD);  // [64][4][2] LN2 partials
    f16* ehid   = eol;                       // overlay

    const int tid = threadIdx.x;
    const int lane = tid & 63, wv = tid >> 6;
    const int lr = lane & 15, lg = lane >> 4;
    const int mb = wv * 16;
    const size_t tok0 = (size_t)blockIdx.x * 64;

    {
        const int tk = tid >> 2, part = tid & 3;
        const f16x8* src = (const f16x8*)(o_in + (tok0 + tk) * 128 + part * 32);
        f16x8* dst = (f16x8*)(eol + tk * EOLS + part * 32);
        dst[0] = src[0]; dst[1] = src[1]; dst[2] = src[2]; dst[3] = src[3];
    }
    __syncthreads();

    {   // upd = o @ Wo (K=128); fused residual -> tv (f16)
        f16x8 a_[4];
        #pragma unroll
        for (int ks = 0; ks < 4; ++ks)
            a_[ks] = *(const f16x8*)(eol + (mb + lr) * EOLS + ks*32 + lg*8);
        #pragma unroll
        for (int nt = 0; nt < 4; ++nt) {
            const int ch = nt * 16 + lr;
            f32x4 c = {0.f,0.f,0.f,0.f};
            #pragma unroll
            for (int ks = 0; ks < 4; ++ks)
                c = __builtin_amdgcn_mfma_f32_16x16x32_f16(a_[ks], *wfrag(FR_WO, 4, nt, ks, lg, lr), c, 0, 0, 0);
            const float bo_c = bo[ch], ga_c = gamma[ch];
            #pragma unroll
            for (int e = 0; e < 4; ++e) {
                const int tk = mb + lg*4 + e;
                etv[tk * ETVS + ch] = (f16)(x[(tok0 + tk)*64 + ch] + ga_c * (c[e] + bo_c));
            }
        }
    }
    __syncthreads();

    {   // LN2 partial stats (4 threads/token), f16x8 vector reads
        const int tk = tid >> 2, q = tid & 3;
        const f16x8* tr = (const f16x8*)(etv + tk * ETVS + q * 16);
        const f16x8 v0 = tr[0], v1 = tr[1];
        float s1 = 0.f, s2 = 0.f;
        #pragma unroll
        for (int j = 0; j < 8; ++j) {
            const float a = (float)v0[j], b = (float)v1[j];
            s1 += a + b; s2 += a*a + b*b;
        }
        erd[(tk*4 + q)*2] = s1; erd[(tk*4 + q)*2 + 1] = s2;
    }
    __syncthreads();
    {   // finalize LN2 -> eh2 (f16)
        const int tk = tid >> 2, q = tid & 3;
        float a1 = 0.f, a2 = 0.f;
        #pragma unroll
        for (int i = 0; i < 4; ++i) { a1 += erd[(tk*4 + i)*2]; a2 += erd[(tk*4 + i)*2 + 1]; }
        const float mean = a1 * 0.015625f;
        const float rstd = rsqrtf(a2 * 0.015625f - mean*mean + 1e-5f);
        const f16* tr = etv + tk * ETVS + q * 16;
        f16* hr = eh2 + tk * EH2S + q * 16;
        #pragma unroll
        for (int j = 0; j < 16; ++j)
            hr[j] = (f16)(((float)tr[j]-mean)*rstd*ln2_s[q*16 + j] + ln2_b[q*16 + j]);
    }
    __syncthreads();

    {   // hid = gelu(h2 @ W1) (K=64); overlays o buffer
        f16x8 a_[2];
        #pragma unroll
        for (int ks = 0; ks < 2; ++ks)
            a_[ks] = *(const f16x8*)(eh2 + (mb + lr) * EH2S + ks*32 + lg*8);
        #pragma unroll
        for (int nt = 0; nt < 8; ++nt) {
            const int ch = nt * 16 + lr;
            f32x4 c = {0.f,0.f,0.f,0.f};
            #pragma unroll
            for (int ks = 0; ks < 2; ++ks)
                c = __builtin_amdgcn_mfma_f32_16x16x32_f16(a_[ks], *wfrag(FR_W1, 2, nt, ks, lg, lr), c, 0, 0, 0);
            const float b1_c = b1[ch];
            #pragma unroll
            for (int e = 0; e < 4; ++e) {
                const int tk = mb + lg*4 + e;
                const float z = c[e] + b1_c;
                const float u = 0.7978845608028654f * (z + 0.044715f * z*z*z);
                ehid[tk * EOLS + ch] = (f16)(z / (1.0f + exp2fast(-2.8853900817779268f * u)));
            }
        }
    }
    __syncthreads();

    {   // oa = hid @ W2 (K=128); final residual (tv f16) -> out
        f16x8 a_[4];
        #pragma unroll
        for (int ks = 0; ks < 4; ++ks)
            a_[ks] = *(const f16x8*)(ehid + (mb + lr) * EOLS + ks*32 + lg*8);
        #pragma unroll
        for (int nt = 0; nt < 4; ++nt) {
            const int ch = nt * 16 + lr;
            f32x4 c = {0.f,0.f,0.f,0.f};
            #pragma unroll
            for (int ks = 0; ks < 4; ++ks)
                c = __builtin_amdgcn_mfma_f32_16x16x32_f16(a_[ks], *wfrag(FR_W2, 4, nt, ks, lg, lr), c, 0, 0, 0);
            const float b2_c = b2[ch], gm_c = gm[ch];
            #pragma unroll
            for (int e = 0; e < 4; ++e) {
                const int tk = mb + lg*4 + e;
                out[(tok0 + tk)*64 + ch] = (float)etv[tk * ETVS + ch] + gm_c * (c[e] + b2_c);
            }
        }
    }
}

extern "C" void kernel_launch(void* const* d_in, const int* in_sizes, int n_in,
                              void* d_out, int out_size, void* d_ws, size_t ws_size,
                              hipStream_t stream) {
    const float* x        = (const float*)d_in[0];
    const float* ln1_s    = (const float*)d_in[1];
    const float* ln1_b    = (const float*)d_in[2];
    const float* Wq       = (const float*)d_in[3];
    const float* Wkv      = (const float*)d_in[4];
    const float* bkv      = (const float*)d_in[5];
    const float* Wo       = (const float*)d_in[6];
    const float* bo       = (const float*)d_in[7];
    const float* gamma    = (const float*)d_in[8];
    const float* ln2_s    = (const float*)d_in[9];
    const float* ln2_b    = (const float*)d_in[10];
    const float* W1       = (const float*)d_in[11];
    const float* b1       = (const float*)d_in[12];
    const float* W2       = (const float*)d_in[13];
    const float* b2       = (const float*)d_in[14];
    const float* gamma_mlp= (const float*)d_in[15];

    // o (f16[65536][128]) aliases d_out (f32[65536][64]); disjoint token partition
    // between k_att writes and k_epi reads/overwrites -> race-free.
    f16* o_buf = (f16*)d_out;
    float* out = (float*)d_out;

    hipLaunchKernelGGL(k_convln, dim3(CONV_BLOCKS + 1024), dim3(256), 0, stream,
                       Wq, Wkv, Wo, W1, W2, x, ln1_s, ln1_b);
    hipLaunchKernelGGL(k_att, dim3(2048), dim3(256), 0, stream,
                       bkv, o_buf);
    hipLaunchKernelGGL(k_epi, dim3(1024), dim3(256), 0, stream,
                       x, o_buf, bo, gamma, ln2_s, ln2_b, b1, b2, gamma_mlp, out);
}

// Round 29
// 54.555 us; speedup vs baseline: 1.0275x; 1.0275x over previous
//
#include <hip/hip_runtime.h>
#include <math.h>

typedef _Float16 f16;
typedef _Float16 f16x2 __attribute__((ext_vector_type(2)));
typedef _Float16 f16x4 __attribute__((ext_vector_type(4)));
typedef _Float16 f16x8 __attribute__((ext_vector_type(8)));
typedef float f32x4 __attribute__((ext_vector_type(4)));

#if defined(__has_builtin)
#if __has_builtin(__builtin_amdgcn_fdot2)
#define USE_FDOT2 1
#endif
#if __has_builtin(__builtin_amdgcn_exp2f)
#define USE_EXP2 1
#endif
#if __has_builtin(__builtin_amdgcn_cvt_pkrtz)
#define USE_PKRTZ 1
#endif
#endif

__device__ __forceinline__ float fdot2f(f16x2 a, f16x2 b, float c) {
#ifdef USE_FDOT2
    return __builtin_amdgcn_fdot2(a, b, c, false);
#else
    return c + (float)a.x * (float)b.x + (float)a.y * (float)b.y;
#endif
}
__device__ __forceinline__ float exp2fast(float a) {
#ifdef USE_EXP2
    return __builtin_amdgcn_exp2f(a);
#else
    return exp2f(a);
#endif
}
__device__ __forceinline__ f16x2 pk2(float a, float b) {
#ifdef USE_PKRTZ
    auto r0 = __builtin_amdgcn_cvt_pkrtz(a, b);
    f16x2 r; __builtin_memcpy(&r, &r0, 4); return r;
#else
    return (f16x2){(f16)a, (f16)b};
#endif
}
__device__ __forceinline__ int f16x2_as_int(f16x2 v) { int r; __builtin_memcpy(&r, &v, 4); return r; }
__device__ __forceinline__ f16x2 int_as_f16x2(int v) { f16x2 r; __builtin_memcpy(&r, &v, 4); return r; }

namespace {
// ---- k_att constants (ql-free: 28160B LDS -> 5 blocks/CU) ----
constexpr int KS  = 40;
constexpr int VTS = 200;
constexpr int OFF_KL = 0;            // 192*40*2 = 15360
constexpr int OFF_VT = 15360;        // 12800 -> 28160
constexpr int ATT_LDS = 28160;       // x5 = 140800 <= 160K -> 5 blocks/CU
constexpr float C1  = 0.2550600f;
constexpr float CZN = -5.7707801f;
constexpr float CZV = 2.5511480f;

// ---- weights in MFMA B-FRAGMENT layout [ot][ks][lg][lr][j] f16 ----
constexpr int FR_WQ  = 0;        // IN=64  OUT=128 -> 8192
constexpr int FR_WKV = 8192;     // IN=64  OUT=256 -> 16384
constexpr int FR_WO  = 24576;    // IN=128 OUT=64  -> 8192
constexpr int FR_W1  = 32768;    // IN=64  OUT=128 -> 8192
constexpr int FR_W2  = 40960;    // IN=128 OUT=64  -> 8192
constexpr int NWF    = 49152;    // total f16 (96 KB)
constexpr int CONV_BLOCKS = NWF / 256;   // 192

// ---- k_epi constants (32 tokens/block, f32 tv) ----
constexpr int EOLS = 136;   // f16/row o & hid
constexpr int ETVS = 66;    // f32/row tv
constexpr int EH2S = 72;    // f16/row h2
constexpr int OFF_EOL = 0;                   // 32*136*2 = 8704
constexpr int OFF_ETV = 8704;                // 32*66*4  = 8448 -> 17152
constexpr int OFF_EH2 = 17152;               // 32*72*2  = 4608 -> 21760
constexpr int OFF_ERD = 21760;               // 32*8*2 f32 = 2048 -> 23808
constexpr int EPI_LDS = 23808;               // -> 6 blocks/CU (LDS-bound)
}

__device__ f16 g_wfrag[NWF];
// g_h in MFMA A-FRAGMENT layout: [tokblk(4096)][ks(2)][lg(4)][lr(16)][j(8)] f16.
__device__ f16 g_h[65536 * 64];

__device__ __forceinline__ const f16x8* hfrag(size_t tokblk, int ks, int lg, int lr) {
    return (const f16x8*)(g_h + (((tokblk * 2 + ks) * 4 + lg) * 16 + lr) * 8);
}
__device__ __forceinline__ const f16x8* wfrag(int base, int nks, int ot, int ks, int lg, int lr) {
    return (const f16x8*)(g_wfrag + base + (((ot * nks + ks) * 4 + lg) * 16 + lr) * 8);
}

// ---------------- Kernel 0 (merged): weight repack + LN1 -> g_h ----------------
__global__ __launch_bounds__(256, 8) void k_convln(
    const float* __restrict__ Wq, const float* __restrict__ Wkv,
    const float* __restrict__ Wo, const float* __restrict__ W1,
    const float* __restrict__ W2,
    const float* __restrict__ x,
    const float* __restrict__ ln1_s, const float* __restrict__ ln1_b) {
    const int bid = blockIdx.x;
    if (bid < CONV_BLOCKS) {
        const int i = bid * 256 + threadIdx.x;      // f16 element index
        const float* src; int IN, OUT, base;
        if (i < FR_WKV)      { src = Wq;  IN = 64;  OUT = 128; base = FR_WQ;  }
        else if (i < FR_WO)  { src = Wkv; IN = 64;  OUT = 256; base = FR_WKV; }
        else if (i < FR_W1)  { src = Wo;  IN = 128; OUT = 64;  base = FR_WO;  }
        else if (i < FR_W2)  { src = W1;  IN = 64;  OUT = 128; base = FR_W1;  }
        else                 { src = W2;  IN = 128; OUT = 64;  base = FR_W2;  }
        const int local = i - base;
        const int j  = local & 7;
        const int lr = (local >> 3) & 15;
        const int lg = (local >> 7) & 3;
        const int nks = IN >> 5;
        const int ks = (local >> 9) & (nks - 1);
        const int ot = local >> (9 + ((nks == 2) ? 1 : 2));
        const int in  = ks * 32 + lg * 8 + j;
        const int out = ot * 16 + lr;
        g_wfrag[i] = (f16)src[in * OUT + out];
        return;
    }
    // LN1 part: 1024 blocks of 64 tokens, 4 threads/token
    const int lb = bid - CONV_BLOCKS;
    const int tid = threadIdx.x;
    const size_t tok = (size_t)lb * 64 + (tid >> 2);
    const int q = tid & 3;
    const float* xr = x + tok * 64 + q * 16;
    float v[16];
    {
        const float4 a = ((const float4*)xr)[0], b = ((const float4*)xr)[1];
        const float4 c = ((const float4*)xr)[2], d = ((const float4*)xr)[3];
        v[0]=a.x; v[1]=a.y; v[2]=a.z; v[3]=a.w;  v[4]=b.x; v[5]=b.y; v[6]=b.z; v[7]=b.w;
        v[8]=c.x; v[9]=c.y; v[10]=c.z; v[11]=c.w; v[12]=d.x; v[13]=d.y; v[14]=d.z; v[15]=d.w;
    }
    float s = 0.f, ss = 0.f;
    #pragma unroll
    for (int j = 0; j < 16; ++j) { s += v[j]; ss += v[j]*v[j]; }
    s  += __shfl_xor(s, 1);  s  += __shfl_xor(s, 2);
    ss += __shfl_xor(ss, 1); ss += __shfl_xor(ss, 2);
    const float mean = s * 0.015625f;
    const float rstd = rsqrtf(ss * 0.015625f - mean*mean + 1e-5f);
    f16x8 p0, p1;
    #pragma unroll
    for (int j = 0; j < 8; ++j) {
        p0[j] = (f16)((v[j]     - mean) * rstd * ln1_s[q*16 + j]     + ln1_b[q*16 + j]);
        p1[j] = (f16)((v[j + 8] - mean) * rstd * ln1_s[q*16 + j + 8] + ln1_b[q*16 + j + 8]);
    }
    const size_t tokblk = tok >> 4;
    const int lr = (int)(tok & 15);
    const int ks = q >> 1, lg0 = (q & 1) * 2;
    *(f16x8*)(g_h + (((tokblk * 2 + ks) * 4 + lg0) * 16 + lr) * 8)     = p0;
    *(f16x8*)(g_h + (((tokblk * 2 + ks) * 4 + lg0 + 1) * 16 + lr) * 8) = p1;
}

// ---------------- Kernel 1: per-(window,head) attention; P AND Q in registers ----------
__global__ __launch_bounds__(256, 5) void k_att(
    const float* __restrict__ bkv,
    f16* __restrict__ o_out)
{
    __shared__ __align__(16) char smem[ATT_LDS];
    f16* kl   = (f16*)(smem + OFF_KL);
    f16* vt   = (f16*)(smem + OFF_VT);

    const int tid  = threadIdx.x;
    const int bid  = blockIdx.x;
    const int w    = bid & 511;
    const int head = bid >> 9;
    const int cb   = head * 32;
    const int n    = w & 255;
    const int t    = w >> 8;

    const int lane = tid & 63, wv = tid >> 6;
    const int lr = lane & 15, lg = lane >> 4;
    const int mA = wv * 32;

    // Phase C: K/V projections -> LDS; Q projection -> registers (B-frag via shuffle)
    f16x8 bq0, bq1;
    {
        #pragma unroll
        for (int mi = 0; mi < 3; ++mi) {
            const int seg = wv * 3 + mi;                    // 0..11
            const int v_ = seg / 6;
            const int t2 = (seg % 6) + ((t == 0) ? 2 : 0);
            int tsrc, tt;
            if (t2 < 2)      { tsrc = t - 1; tt = t2 + 2; }
            else if (t2 < 6) { tsrc = t;     tt = t2 - 2; }
            else             { tsrc = t + 1; tt = t2 - 6; }
            const size_t tokblk = (size_t)(v_ * 8 + tsrc * 4 + tt) * 256 + n;
            const int mb = seg * 16;
            #pragma unroll
            for (int nt = 0; nt < 2; ++nt) {
                f32x4 ck = {0.f,0.f,0.f,0.f}, cv = {0.f,0.f,0.f,0.f};
                #pragma unroll
                for (int ks = 0; ks < 2; ++ks) {
                    const f16x8 af = *hfrag(tokblk, ks, lg, lr);
                    const f16x8 bk = *wfrag(FR_WKV, 2, head*2 + nt, ks, lg, lr);
                    const f16x8 bv = *wfrag(FR_WKV, 2, 8 + head*2 + nt, ks, lg, lr);
                    ck = __builtin_amdgcn_mfma_f32_16x16x32_f16(af, bk, ck, 0, 0, 0);
                    cv = __builtin_amdgcn_mfma_f32_16x16x32_f16(af, bv, cv, 0, 0, 0);
                }
                const float bk_b = bkv[cb + nt*16 + lr];
                const float bv_b = bkv[128 + cb + nt*16 + lr];
                #pragma unroll
                for (int e = 0; e < 4; ++e) {
                    const int row = mb + lg*4 + e;
                    kl[row * KS + nt*16 + lr] = (f16)(ck[e] + bk_b);
                    vt[(nt*16 + lr) * VTS + row] = (f16)(cv[e] + bv_b);
                }
            }
        }
        // Q: wave-local shuffle transpose from C-layout to B-frag
        #pragma unroll
        for (int mi = 0; mi < 2; ++mi) {
            const int qm = wv * 2 + mi;
            const int v_ = qm >> 2, tt = qm & 3;
            const size_t tokblk = (size_t)(v_ * 8 + t * 4 + tt) * 256 + n;
            int pkA[2], pkB[2];
            #pragma unroll
            for (int nt = 0; nt < 2; ++nt) {
                f32x4 cq = {0.f,0.f,0.f,0.f};
                #pragma unroll
                for (int ks = 0; ks < 2; ++ks) {
                    const f16x8 af = *hfrag(tokblk, ks, lg, lr);
                    const f16x8 bq = *wfrag(FR_WQ, 2, head*2 + nt, ks, lg, lr);
                    cq = __builtin_amdgcn_mfma_f32_16x16x32_f16(af, bq, cq, 0, 0, 0);
                }
                pkA[nt] = f16x2_as_int(pk2(cq[0], cq[1]));
                pkB[nt] = f16x2_as_int(pk2(cq[2], cq[3]));
            }
            f16x8 bq_;
            #pragma unroll
            for (int j = 0; j < 8; ++j) {
                const int sl = (lr >> 2) * 16 + (lg & 1) * 8 + j;
                const int a0 = __shfl(pkA[0], sl), b0 = __shfl(pkB[0], sl);
                const int a1 = __shfl(pkA[1], sl), b1 = __shfl(pkB[1], sl);
                const int s0 = (lr & 2) ? b0 : a0;
                const int s1 = (lr & 2) ? b1 : a1;
                const f16x2 vv = int_as_f16x2((lg >= 2) ? s1 : s0);
                bq_[j] = (lr & 1) ? vv.y : vv.x;
            }
            if (mi == 0) bq0 = bq_; else bq1 = bq_;
        }
    }

    // pz from register q (B-frag layout)
    float pz0, pz1;
    {
        float s0 = 0.f, s1 = 0.f;
        #pragma unroll
        for (int j = 0; j < 8; ++j) {
            const float wgt = bkv[cb + lg*8 + j];
            s0 += (float)bq0[j] * wgt;
            s1 += (float)bq1[j] * wgt;
        }
        s0 += __shfl_xor(s0, 16); s0 += __shfl_xor(s0, 32);
        s1 += __shfl_xor(s1, 16); s1 += __shfl_xor(s1, 32);
        pz0 = exp2fast(fmaf(s0, C1, CZV));
        pz1 = exp2fast(fmaf(s1, C1, CZV));
    }

    __syncthreads();   // kl/vt ready (the kernel's only barrier)

    f32x4 oc00 = {0.f,0.f,0.f,0.f}, oc01 = {0.f,0.f,0.f,0.f};
    f32x4 oc10 = {0.f,0.f,0.f,0.f}, oc11 = {0.f,0.f,0.f,0.f};
    float l0 = 0.f, l1 = 0.f;

    #pragma unroll 1
    for (int kk = 0; kk < 6; ++kk) {
        const f16x8 ak0 = *(const f16x8*)(kl + (kk*32 + lr) * KS + lg * 8);
        const f16x8 ak1 = *(const f16x8*)(kl + (kk*32 + 16 + lr) * KS + lg * 8);
        const f32x4 ct00 = __builtin_amdgcn_mfma_f32_16x16x32_f16(ak0, bq0, (f32x4){0.f,0.f,0.f,0.f}, 0, 0, 0);
        const f32x4 ct01 = __builtin_amdgcn_mfma_f32_16x16x32_f16(ak0, bq1, (f32x4){0.f,0.f,0.f,0.f}, 0, 0, 0);
        const f32x4 ct10 = __builtin_amdgcn_mfma_f32_16x16x32_f16(ak1, bq0, (f32x4){0.f,0.f,0.f,0.f}, 0, 0, 0);
        const f32x4 ct11 = __builtin_amdgcn_mfma_f32_16x16x32_f16(ak1, bq1, (f32x4){0.f,0.f,0.f,0.f}, 0, 0, 0);

        float p00[4], p01[4], p10[4], p11[4];
        #pragma unroll
        for (int e = 0; e < 4; ++e) {
            p00[e] = exp2fast(fmaf(ct00[e], C1, CZN));
            p01[e] = exp2fast(fmaf(ct01[e], C1, CZN));
            p10[e] = exp2fast(fmaf(ct10[e], C1, CZN));
            p11[e] = exp2fast(fmaf(ct11[e], C1, CZN));
        }
        #pragma unroll
        for (int e = 0; e < 4; ++e) { l0 += p00[e] + p10[e]; l1 += p01[e] + p11[e]; }

        int pk0[4], pk1[4];
        #pragma unroll
        for (int e = 0; e < 4; ++e) {
            pk0[e] = f16x2_as_int(pk2(p00[e], p10[e]));
            pk1[e] = f16x2_as_int(pk2(p01[e], p11[e]));
        }
        f16x8 bp0, bp1;
        #pragma unroll
        for (int j = 0; j < 8; ++j) {
            const int sl = ((lg & 1) * 2 + (j >> 2)) * 16 + lr;
            const f16x2 v0 = int_as_f16x2(__shfl(pk0[j & 3], sl));
            const f16x2 v1 = int_as_f16x2(__shfl(pk1[j & 3], sl));
            bp0[j] = (lg < 2) ? v0.x : v0.y;
            bp1[j] = (lg < 2) ? v1.x : v1.y;
        }

        const f16x8 av0 = *(const f16x8*)(vt + lr * VTS + kk*32 + lg*8);
        const f16x8 av1 = *(const f16x8*)(vt + (16 + lr) * VTS + kk*32 + lg*8);
        oc00 = __builtin_amdgcn_mfma_f32_16x16x32_f16(av0, bp0, oc00, 0, 0, 0);
        oc01 = __builtin_amdgcn_mfma_f32_16x16x32_f16(av0, bp1, oc01, 0, 0, 0);
        oc10 = __builtin_amdgcn_mfma_f32_16x16x32_f16(av1, bp0, oc10, 0, 0, 0);
        oc11 = __builtin_amdgcn_mfma_f32_16x16x32_f16(av1, bp1, oc11, 0, 0, 0);
    }

    l0 += __shfl_xor(l0, 16); l0 += __shfl_xor(l0, 32);
    l1 += __shfl_xor(l1, 16); l1 += __shfl_xor(l1, 32);

    const float inv0 = 1.0f / (l0 + pz0), pzn0 = pz0 * inv0;
    const float inv1 = 1.0f / (l1 + pz1), pzn1 = pz1 * inv1;

    #define EPI_TILE(CC, MT, QT, INVQ, PZQ) { \
        const int q = mA + (QT) * 16 + lr; \
        const int v2 = q >> 6, tt2 = (q >> 4) & 3, nn2 = (q >> 2) & 3, dd2 = q & 3; \
        const size_t tk = ((size_t)(v2 * 8 + t * 4 + tt2) * 1024 + n * 4 + nn2) * 4 + dd2; \
        float oo[4]; \
        _Pragma("unroll") \
        for (int e = 0; e < 4; ++e) { \
            const int ch = (MT) * 16 + lg * 4 + e; \
            oo[e] = fmaf(PZQ, bkv[128 + cb + ch], CC[e] * (INVQ)); \
        } \
        const f16x2 lo_ = pk2(oo[0], oo[1]), hi_ = pk2(oo[2], oo[3]); \
        const f16x4 st_ = {lo_.x, lo_.y, hi_.x, hi_.y}; \
        *(f16x4*)(o_out + tk * 128 + cb + (MT) * 16 + lg * 4) = st_; \
    }
    EPI_TILE(oc00, 0, 0, inv0, pzn0)
    EPI_TILE(oc01, 0, 1, inv1, pzn1)
    EPI_TILE(oc10, 1, 0, inv0, pzn0)
    EPI_TILE(oc11, 1, 1, inv1, pzn1)
    #undef EPI_TILE
}

// ---------------- Kernel 2: MFMA epilogue, 32 tokens/block x 2048 blocks ----------
// 2 waves share an m-tile and split output-channel tiles (hf = wv&1) -> per-block
// critical path halves; 2048 blocks give 2+ co-resident rounds. tv f32.
__global__ __launch_bounds__(256, 4) void k_epi(
    const float* __restrict__ x, const f16* __restrict__ o_in,
    const float* __restrict__ bo, const float* __restrict__ gamma,
    const float* __restrict__ ln2_s, const float* __restrict__ ln2_b,
    const float* __restrict__ b1, const float* __restrict__ b2,
    const float* __restrict__ gm, float* __restrict__ out)
{
    __shared__ __align__(16) char smem[EPI_LDS];
    f16* eol    = (f16*)(smem + OFF_EOL);    // [32][136] o rows; hid overlays
    float* etv  = (float*)(smem + OFF_ETV);  // [32][66] tv f32
    f16* eh2    = (f16*)(smem + OFF_EH2);    // [32][72] LN2 output
    float* erd  = (float*)(smem + OFF_ERD);  // [32][8][2] LN2 partials
    f16* ehid   = eol;                       // overlay

    const int tid = threadIdx.x;
    const int lane = tid & 63, wv = tid >> 6;
    const int lr = lane & 15, lg = lane >> 4;
    const int miw = wv >> 1, hf = wv & 1;    // m-tile, channel-half
    const int mb = miw * 16;
    const size_t tok0 = (size_t)blockIdx.x * 32;

    {   // Phase A: coalesced o -> LDS; 16 f16 per thread (32 tok x 128 f16)
        const int tk = tid >> 3, part = tid & 7;
        const f16x8* src = (const f16x8*)(o_in + (tok0 + tk) * 128 + part * 16);
        f16x8* dst = (f16x8*)(eol + tk * EOLS + part * 16);
        dst[0] = src[0]; dst[1] = src[1];
    }
    __syncthreads();

    {   // Phase B: upd = o @ Wo (K=128); wave handles nt in {hf*2, hf*2+1}
        f16x8 a_[4];
        #pragma unroll
        for (int ks = 0; ks < 4; ++ks)
            a_[ks] = *(const f16x8*)(eol + (mb + lr) * EOLS + ks*32 + lg*8);
        #pragma unroll
        for (int ni = 0; ni < 2; ++ni) {
            const int nt = hf * 2 + ni;
            const int ch = nt * 16 + lr;
            f32x4 c = {0.f,0.f,0.f,0.f};
            #pragma unroll
            for (int ks = 0; ks < 4; ++ks)
                c = __builtin_amdgcn_mfma_f32_16x16x32_f16(a_[ks], *wfrag(FR_WO, 4, nt, ks, lg, lr), c, 0, 0, 0);
            const float bo_c = bo[ch], ga_c = gamma[ch];
            #pragma unroll
            for (int e = 0; e < 4; ++e) {
                const int tk = mb + lg*4 + e;
                etv[tk * ETVS + ch] = x[(tok0 + tk)*64 + ch] + ga_c * (c[e] + bo_c);
            }
        }
    }
    __syncthreads();

    {   // Phase C1: LN2 partial stats (8 threads/token, 8 channels each)
        const int tk = tid >> 3, q = tid & 7;
        const float* tr = etv + tk * ETVS + q * 8;
        float s1 = 0.f, s2 = 0.f;
        #pragma unroll
        for (int j = 0; j < 8; ++j) { const float v = tr[j]; s1 += v; s2 += v*v; }
        erd[(tk*8 + q)*2] = s1; erd[(tk*8 + q)*2 + 1] = s2;
    }
    __syncthreads();
    {   // Phase C2: finalize LN2 -> eh2 (f16)
        const int tk = tid >> 3, q = tid & 7;
        float a1 = 0.f, a2 = 0.f;
        #pragma unroll
        for (int i = 0; i < 8; ++i) { a1 += erd[(tk*8 + i)*2]; a2 += erd[(tk*8 + i)*2 + 1]; }
        const float mean = a1 * 0.015625f;
        const float rstd = rsqrtf(a2 * 0.015625f - mean*mean + 1e-5f);
        const float* tr = etv + tk * ETVS + q * 8;
        f16* hr = eh2 + tk * EH2S + q * 8;
        #pragma unroll
        for (int j = 0; j < 8; ++j)
            hr[j] = (f16)((tr[j]-mean)*rstd*ln2_s[q*8 + j] + ln2_b[q*8 + j]);
    }
    __syncthreads();

    {   // Phase D: hid = gelu(h2 @ W1) (K=64); wave handles nt in hf*4 .. +4
        f16x8 a_[2];
        #pragma unroll
        for (int ks = 0; ks < 2; ++ks)
            a_[ks] = *(const f16x8*)(eh2 + (mb + lr) * EH2S + ks*32 + lg*8);
        #pragma unroll
        for (int ni = 0; ni < 4; ++ni) {
            const int nt = hf * 4 + ni;
            const int ch = nt * 16 + lr;
            f32x4 c = {0.f,0.f,0.f,0.f};
            #pragma unroll
            for (int ks = 0; ks < 2; ++ks)
                c = __builtin_amdgcn_mfma_f32_16x16x32_f16(a_[ks], *wfrag(FR_W1, 2, nt, ks, lg, lr), c, 0, 0, 0);
            const float b1_c = b1[ch];
            #pragma unroll
            for (int e = 0; e < 4; ++e) {
                const int tk = mb + lg*4 + e;
                const float z = c[e] + b1_c;
                const float u = 0.7978845608028654f * (z + 0.044715f * z*z*z);
                ehid[tk * EOLS + ch] = (f16)(z / (1.0f + exp2fast(-2.8853900817779268f * u)));
            }
        }
    }
    __syncthreads();

    {   // Phase E: oa = hid @ W2 (K=128); wave handles nt in {hf*2, hf*2+1}
        f16x8 a_[4];
        #pragma unroll
        for (int ks = 0; ks < 4; ++ks)
            a_[ks] = *(const f16x8*)(ehid + (mb + lr) * EOLS + ks*32 + lg*8);
        #pragma unroll
        for (int ni = 0; ni < 2; ++ni) {
            const int nt = hf * 2 + ni;
            const int ch = nt * 16 + lr;
            f32x4 c = {0.f,0.f,0.f,0.f};
            #pragma unroll
            for (int ks = 0; ks < 4; ++ks)
                c = __builtin_amdgcn_mfma_f32_16x16x32_f16(a_[ks], *wfrag(FR_W2, 4, nt, ks, lg, lr), c, 0, 0, 0);
            const float b2_c = b2[ch], gm_c = gm[ch];
            #pragma unroll
            for (int e = 0; e < 4; ++e) {
                const int tk = mb + lg*4 + e;
                out[(tok0 + tk)*64 + ch] = etv[tk * ETVS + ch] + gm_c * (c[e] + b2_c);
            }
        }
    }
}

extern "C" void kernel_launch(void* const* d_in, const int* in_sizes, int n_in,
                              void* d_out, int out_size, void* d_ws, size_t ws_size,
                              hipStream_t stream) {
    const float* x        = (const float*)d_in[0];
    const float* ln1_s    = (const float*)d_in[1];
    const float* ln1_b    = (const float*)d_in[2];
    const float* Wq       = (const float*)d_in[3];
    const float* Wkv      = (const float*)d_in[4];
    const float* bkv      = (const float*)d_in[5];
    const float* Wo       = (const float*)d_in[6];
    const float* bo       = (const float*)d_in[7];
    const float* gamma    = (const float*)d_in[8];
    const float* ln2_s    = (const float*)d_in[9];
    const float* ln2_b    = (const float*)d_in[10];
    const float* W1       = (const float*)d_in[11];
    const float* b1       = (const float*)d_in[12];
    const float* W2       = (const float*)d_in[13];
    const float* b2       = (const float*)d_in[14];
    const float* gamma_mlp= (const float*)d_in[15];

    // o (f16[65536][128]) aliases d_out (f32[65536][64]); disjoint token partition
    // between k_att writes and k_epi reads/overwrites -> race-free.
    f16* o_buf = (f16*)d_out;
    float* out = (float*)d_out;

    hipLaunchKernelGGL(k_convln, dim3(CONV_BLOCKS + 1024), dim3(256), 0, stream,
                       Wq, Wkv, Wo, W1, W2, x, ln1_s, ln1_b);
    hipLaunchKernelGGL(k_att, dim3(2048), dim3(256), 0, stream,
                       bkv, o_buf);
    hipLaunchKernelGGL(k_epi, dim3(2048), dim3(256), 0, stream,
                       x, o_buf, bo, gamma, ln2_s, ln2_b, b1, b2, gamma_mlp, out);
}